// Round 1
// 664.903 us; speedup vs baseline: 1.0029x; 1.0029x over previous
//
#include <hip/hip_runtime.h>
#include <math.h>

// GlobalAttentionPool: fused linear-score + segment softmax + weighted pool.
//
// Round-3 restructure vs round-2 (667 us):
//  Diagnosis: kernel is latency/parallelism-bound, not BW-bound. Evidence:
//  (a) gap kernel absent from rocprof top-5 (all 316-319us fills) => kernel
//      <= 315us => <= 1.7 TB/s on 512 MB mandatory traffic (25% of peak);
//  (b) round-1->2 octupled in-flight bytes/wave for only 1.12x => not
//      in-flight-bytes-bound. Invariant across rounds: 1024 blocks
//      (4/CU, 16 waves/CU) each with ~122 serially-dependent wave-iters.
//  Fix: split every segment into 8 chunks -> 8192 independent blocks with
//  8x shorter online-softmax chains, writing partial (m, l, acc[128])
//  states to workspace; tiny merge kernel combines them (associative).
//  x is still read exactly once (512 MB). Also: tile-level single rescale
//  (one alpha per 8-row tile) so the 4 exps per tile are independent,
//  shortening the per-iter VALU dependency chain.

#define DIM 128
#define CHUNKS 8          // blocks per segment; grid = B*CHUNKS = 8192
#define NEG_HUGE (-3.0e38f)

// ---- Kernel 1: segment offset table from sorted batch -----------------
// off[s] = first index i with batch[i] >= s, for s in [0, B]; off[B] = N.
__global__ void seg_offsets_kernel(const int* __restrict__ batch,
                                   int* __restrict__ off, int N, int B) {
    int i = blockIdx.x * blockDim.x + threadIdx.x;
    if (i >= N) return;
    int bi = batch[i];
    int bp = (i == 0) ? -1 : batch[i - 1];
    for (int s = bp + 1; s <= bi; ++s) off[s] = i;
    if (i == N - 1) {
        for (int s = bi + 1; s <= B; ++s) off[s] = N;
    }
}

// ---- Kernel 2: per-chunk online-softmax partial state -----------------
// Each block handles chunk c of segment s (rows ~len/CHUNKS), producing a
// single merged partial (m, l, acc[DIM]) written to workspace.
__global__ __launch_bounds__(256) void gap_partial_kernel(
    const float* __restrict__ x,
    const int*   __restrict__ off,
    const float* __restrict__ W,
    const float* __restrict__ bias,
    float*       __restrict__ pm,    // [B*CHUNKS]
    float*       __restrict__ pl,    // [B*CHUNKS]
    float*       __restrict__ pacc)  // [B*CHUNKS][DIM]
{
    const int blk   = blockIdx.x;
    const int seg   = blk >> 3;            // / CHUNKS
    const int chunk = blk & (CHUNKS - 1);
    const int tid  = threadIdx.x;
    const int wave = tid >> 6;   // 0..3
    const int lane = tid & 63;
    const int half = lane >> 5;  // which row of the float4-load pair
    const int hl   = lane & 31;  // lane within 32-lane row group

    const int s0  = off[seg];
    const int s1  = off[seg + 1];
    const int len = s1 - s0;
    const int start = s0 + (len * chunk) / CHUNKS;
    const int end   = s0 + (len * (chunk + 1)) / CHUNKS;

    // Lane hl of each half holds W[4*hl .. 4*hl+3].
    const float4 wv = ((const float4*)W)[hl];
    const float  b0 = bias[0];

    // Online-softmax state per (wave, half): acc distributed over 32 lanes.
    float  m = NEG_HUGE;
    float  l = 0.0f;
    float4 acc = make_float4(0.f, 0.f, 0.f, 0.f);

    // Tile: 8 rows per wave-iteration (k=0..3, 2 rows per float4 load),
    // 32 rows per block-iteration.
    int p = start + wave * 8;

    float4 xv[4];
    #pragma unroll
    for (int k = 0; k < 4; ++k) {
        int row = p + 2 * k + half;
        xv[k] = (row < end) ? ((const float4*)(x + (size_t)row * DIM))[hl]
                            : make_float4(0.f, 0.f, 0.f, 0.f);
    }

    for (; p < end; p += 32) {
        // Prefetch next tile while we reduce the current one.
        float4 xn[4];
        #pragma unroll
        for (int k = 0; k < 4; ++k) {
            int row = p + 32 + 2 * k + half;
            xn[k] = (row < end) ? ((const float4*)(x + (size_t)row * DIM))[hl]
                                : make_float4(0.f, 0.f, 0.f, 0.f);
        }

        // Partial dots for 8 rows (4 per half-wave).
        float s[4];
        #pragma unroll
        for (int k = 0; k < 4; ++k)
            s[k] = xv[k].x * wv.x + xv[k].y * wv.y + xv[k].z * wv.z + xv[k].w * wv.w;

        // Batched butterfly within each 32-lane half (masks <32 keep halves closed).
        #pragma unroll
        for (int offd = 16; offd > 0; offd >>= 1) {
            #pragma unroll
            for (int k = 0; k < 4; ++k)
                s[k] += __shfl_xor(s[k], offd, 64);
        }

        // Tile-level single-rescale online update: one alpha per 8-row
        // tile; the 4 exp(sk - tm) are independent (no serial m-chain).
        float sk[4];
        float tm = m;
        #pragma unroll
        for (int k = 0; k < 4; ++k) {
            int row = p + 2 * k + half;
            sk[k] = (row < end) ? (s[k] + b0) : NEG_HUGE;
            tm = fmaxf(tm, sk[k]);
        }
        float alpha = __expf(m - tm);   // empty state: exp(0)=1 while l=0
        float wsum = 0.0f;
        float4 a2 = make_float4(0.f, 0.f, 0.f, 0.f);
        #pragma unroll
        for (int k = 0; k < 4; ++k) {
            int  row = p + 2 * k + half;
            float w  = (row < end) ? __expf(sk[k] - tm) : 0.0f;
            wsum += w;
            a2.x += w * xv[k].x;
            a2.y += w * xv[k].y;
            a2.z += w * xv[k].z;
            a2.w += w * xv[k].w;
            xv[k] = xn[k];
        }
        l     = l * alpha + wsum;
        acc.x = acc.x * alpha + a2.x;
        acc.y = acc.y * alpha + a2.y;
        acc.z = acc.z * alpha + a2.z;
        acc.w = acc.w * alpha + a2.w;
        m     = tm;
    }

    // ---- Merge 8 per-(wave,half) states into one block partial ----
    __shared__ float sm[8];
    __shared__ float sl[8];
    __shared__ float sacc[8][DIM];

    const int sid = wave * 2 + half;
    sacc[sid][4 * hl + 0] = acc.x;
    sacc[sid][4 * hl + 1] = acc.y;
    sacc[sid][4 * hl + 2] = acc.z;
    sacc[sid][4 * hl + 3] = acc.w;
    if (hl == 0) { sm[sid] = m; sl[sid] = l; }
    __syncthreads();

    if (tid < DIM) {
        float m_tot = NEG_HUGE;
        #pragma unroll
        for (int h = 0; h < 8; ++h) m_tot = fmaxf(m_tot, sm[h]);
        float num = 0.0f, den = 0.0f;
        #pragma unroll
        for (int h = 0; h < 8; ++h) {
            float a = __expf(sm[h] - m_tot);  // both NEG_HUGE -> exp(0)=1, but l=acc=0
            num += sacc[h][tid] * a;
            den += sl[h] * a;
        }
        pacc[(size_t)blk * DIM + tid] = num;
        if (tid == 0) { pm[blk] = m_tot; pl[blk] = den; }
    }
}

// ---- Kernel 3: merge CHUNKS partials per segment ----------------------
__global__ __launch_bounds__(128) void gap_merge_kernel(
    const float* __restrict__ pm,
    const float* __restrict__ pl,
    const float* __restrict__ pacc,
    float*       __restrict__ out)
{
    const int seg = blockIdx.x;
    const int d   = threadIdx.x;

    float ms[CHUNKS];
    float mt = NEG_HUGE;
    #pragma unroll
    for (int c = 0; c < CHUNKS; ++c) {
        ms[c] = pm[seg * CHUNKS + c];
        mt = fmaxf(mt, ms[c]);
    }
    float num = 0.0f, den = 0.0f;
    #pragma unroll
    for (int c = 0; c < CHUNKS; ++c) {
        float a = __expf(ms[c] - mt);   // all-empty segment: exp(0)=1, l=acc=0
        num += pacc[(size_t)(seg * CHUNKS + c) * DIM + d] * a;
        den += pl[seg * CHUNKS + c] * a;
    }
    // Matches reference attn = ex / (seg_sum + 1e-16); empty segment -> 0.
    out[(size_t)seg * DIM + d] = num / (den + 1e-16f);
}

extern "C" void kernel_launch(void* const* d_in, const int* in_sizes, int n_in,
                              void* d_out, int out_size, void* d_ws, size_t ws_size,
                              hipStream_t stream) {
    const float* x     = (const float*)d_in[0];
    // d_in[1] = edge_index (unused by the forward math)
    const int*   batch = (const int*)d_in[2];
    const float* W     = (const float*)d_in[3];
    const float* bias  = (const float*)d_in[4];
    float*       out   = (float*)d_out;

    const int N = in_sizes[2];          // number of nodes
    const int B = out_size / DIM;       // number of segments

    // Workspace layout: off[B+1] ints | pm[B*C] | pl[B*C] | pacc[B*C*DIM]
    // Total ~4.3 MB for B=1024, CHUNKS=8.
    int*   off = (int*)d_ws;
    size_t offb = (((size_t)(B + 1) * sizeof(int)) + 255) & ~(size_t)255;
    float* pm   = (float*)((char*)d_ws + offb);
    float* pl   = pm + (size_t)B * CHUNKS;
    float* pacc = pl + (size_t)B * CHUNKS;

    seg_offsets_kernel<<<(N + 255) / 256, 256, 0, stream>>>(batch, off, N, B);
    gap_partial_kernel<<<B * CHUNKS, 256, 0, stream>>>(x, off, W, bias, pm, pl, pacc);
    gap_merge_kernel<<<B, 128, 0, stream>>>(pm, pl, pacc, out);
}